// Round 2
// baseline (1882.938 us; speedup 1.0000x reference)
//
#include <hip/hip_runtime.h>
#include <hip/hip_bf16.h>
#include <stdint.h>

typedef __bf16 bf16_t;
typedef __bf16 bf16x8 __attribute__((ext_vector_type(8)));
typedef float f32x4 __attribute__((ext_vector_type(4)));

__device__ __forceinline__ bf16x8 ldb8(const bf16_t* p) {
    return *reinterpret_cast<const bf16x8*>(p);
}

__global__ __launch_bounds__(256) void zerof(float* __restrict__ p, int n) {
    int i = blockIdx.x * 256 + threadIdx.x;
    if (i < n) p[i] = 0.f;
}

// fp32 -> (bf16 hi, bf16 lo) split; hi+lo reproduces fp32 to ~2^-17 rel.
__global__ __launch_bounds__(256) void split_k(const float* __restrict__ in,
                                               bf16_t* __restrict__ hi,
                                               bf16_t* __restrict__ lo, long n) {
    long i = (long)blockIdx.x * 256 + threadIdx.x;
    if (i >= n) return;
    float v = in[i];
    bf16_t h = (bf16_t)v;
    hi[i] = h;
    lo[i] = (bf16_t)(v - (float)h);
}

// w [27][Cin][Cout] fp32 -> wt [27][Cout][Cin] bf16 hi/lo (B-fragment friendly:
// 8 consecutive Cin elems per MFMA fragment = one 16B load). Write-coalesced.
__global__ __launch_bounds__(256) void wtrans(const float* __restrict__ w,
                                              bf16_t* __restrict__ hi,
                                              bf16_t* __restrict__ lo,
                                              int Cin, int Cout) {
    long i = (long)blockIdx.x * 256 + threadIdx.x;
    long total = 27L * Cin * Cout;
    if (i >= total) return;
    int ci = (int)(i % Cin);
    long t = i / Cin;
    int co = (int)(t % Cout);
    int k  = (int)(t / Cout);
    float v = w[((long)k * Cin + ci) * Cout + co];
    bf16_t h = (bf16_t)v;
    hi[i] = h;
    lo[i] = (bf16_t)(v - (float)h);
}

// Gather-GEMM with fused BN-stats epilogue.
// Block = 256 thr = 4 waves.
//  CSPLIT=4: block covers RT*16 rows x COUT cols; wave w owns col tiles
//            [w*CT, (w+1)*CT). All waves share the same rows (same ballot skip).
//  CSPLIT=1: block covers 4*RT*16 rows; wave w owns rows [w*RT*16, ...), all cols.
// 3-term split-bf16: hiA*hiB + hiA*loB + loA*hiB (drops loA*loB ~ 2^-32).
template <int CIN, int COUT, int RT, int CSPLIT>
__global__ __launch_bounds__(256) void conv_mfma(
    const bf16_t* __restrict__ fhi, const bf16_t* __restrict__ flo,
    const int* __restrict__ nb,
    const bf16_t* __restrict__ whi, const bf16_t* __restrict__ wlo,
    const bf16_t* __restrict__ zrow,
    float* __restrict__ out, float* __restrict__ stats, int M) {
    constexpr int CT = COUT / 16 / CSPLIT;          // col tiles per wave
    constexpr int KT = CIN / 32;
    constexpr int ROWS_PER_BLOCK = RT * 16 * (4 / CSPLIT);
    const int lane = threadIdx.x & 63;
    const int wave = threadIdx.x >> 6;
    const int quad = lane >> 4;
    const int r16  = lane & 15;
    const int rowbase = blockIdx.x * ROWS_PER_BLOCK + (CSPLIT == 4 ? 0 : wave * RT * 16);
    const int colbase = (CSPLIT == 4 ? wave * CT * 16 : 0);

    f32x4 acc[RT][CT];
#pragma unroll
    for (int t = 0; t < RT; t++)
#pragma unroll
        for (int c = 0; c < CT; c++) acc[t][c] = f32x4{0.f, 0.f, 0.f, 0.f};

    int row[RT];
#pragma unroll
    for (int t = 0; t < RT; t++) row[t] = rowbase + t * 16 + r16;

    for (int k = 0; k < 27; k++) {
        int idx[RT];
        bool anyl = false;
#pragma unroll
        for (int t = 0; t < RT; t++) {
            idx[t] = nb[(long)k * M + row[t]];
            anyl = anyl || (idx[t] >= 0);
        }
        if (__ballot(anyl) == 0ull) continue;  // plane-structured wave-uniform skip
        const bf16_t* ah[RT];
        const bf16_t* al[RT];
#pragma unroll
        for (int t = 0; t < RT; t++) {
            ah[t] = (idx[t] >= 0 ? fhi + (long)idx[t] * CIN : zrow) + quad * 8;
            al[t] = (idx[t] >= 0 ? flo + (long)idx[t] * CIN : zrow) + quad * 8;
        }
        const bf16_t* wh = whi + (long)k * COUT * CIN + (long)(colbase + r16) * CIN + quad * 8;
        const bf16_t* wl = wlo + (long)k * COUT * CIN + (long)(colbase + r16) * CIN + quad * 8;
#pragma unroll
        for (int kk = 0; kk < KT; kk++) {
            bf16x8 AH[RT], AL[RT];
#pragma unroll
            for (int t = 0; t < RT; t++) {
                AH[t] = ldb8(ah[t] + kk * 32);
                AL[t] = ldb8(al[t] + kk * 32);
            }
#pragma unroll
            for (int c = 0; c < CT; c++) {
                bf16x8 BH = ldb8(wh + (long)c * 16 * CIN + kk * 32);
                bf16x8 BL = ldb8(wl + (long)c * 16 * CIN + kk * 32);
#pragma unroll
                for (int t = 0; t < RT; t++) {
                    acc[t][c] = __builtin_amdgcn_mfma_f32_16x16x32_bf16(AH[t], BH, acc[t][c], 0, 0, 0);
                    acc[t][c] = __builtin_amdgcn_mfma_f32_16x16x32_bf16(AH[t], BL, acc[t][c], 0, 0, 0);
                    acc[t][c] = __builtin_amdgcn_mfma_f32_16x16x32_bf16(AL[t], BH, acc[t][c], 0, 0, 0);
                }
            }
        }
    }
    // D layout: row = quad*4 + reg, col = lane&15 (m89/m91-verified)
#pragma unroll
    for (int t = 0; t < RT; t++)
#pragma unroll
        for (int c = 0; c < CT; c++)
#pragma unroll
            for (int r = 0; r < 4; r++)
                out[(long)(rowbase + t * 16 + quad * 4 + r) * COUT + colbase + c * 16 + r16] =
                    acc[t][c][r];
    // Fused BN stats: per-column sum & sumsq over this wave's rows, quad-reduced.
#pragma unroll
    for (int c = 0; c < CT; c++) {
        float s = 0.f, q = 0.f;
#pragma unroll
        for (int t = 0; t < RT; t++)
#pragma unroll
            for (int r = 0; r < 4; r++) {
                float v = acc[t][c][r];
                s += v;
                q = fmaf(v, v, q);
            }
        s += __shfl_xor(s, 16);
        s += __shfl_xor(s, 32);
        q += __shfl_xor(q, 16);
        q += __shfl_xor(q, 32);
        if (quad == 0) {
            atomicAdd(&stats[colbase + c * 16 + r16], s);
            atomicAdd(&stats[COUT + colbase + c * 16 + r16], q);
        }
    }
}

// BN(train) + optional residual + ReLU; writes bf16 hi/lo feature (or final fp32)
__global__ __launch_bounds__(256) void bn_apply(
    const float* __restrict__ f, const float* __restrict__ sums,
    const float* __restrict__ g, const float* __restrict__ bta,
    const bf16_t* __restrict__ idnh, const bf16_t* __restrict__ idnl,
    bf16_t* __restrict__ outh, bf16_t* __restrict__ outl,
    float* __restrict__ outf, long total, int C, float invM) {
    long i = (long)blockIdx.x * 256 + threadIdx.x;
    if (i >= total) return;
    int col = (int)(i & (C - 1));
    float mu = sums[col] * invM;
    float var = sums[C + col] * invM - mu * mu;
    if (var < 0.f) var = 0.f;
    float sc = g[col] * rsqrtf(var + 1e-5f);
    float v = (f[i] - mu) * sc + bta[col];
    if (idnh) v += (float)idnh[i] + (float)idnl[i];
    v = fmaxf(v, 0.f);
    if (outf) {
        outf[i] = v;
    } else {
        bf16_t h = (bf16_t)v;
        outh[i] = h;
        outl[i] = (bf16_t)(v - (float)h);
    }
}

extern "C" void kernel_launch(void* const* d_in, const int* in_sizes, int n_in,
                              void* d_out, int out_size, void* d_ws, size_t ws_size,
                              hipStream_t stream) {
    (void)n_in; (void)out_size; (void)ws_size;
    const float* x    = (const float*)d_in[0];
    const float* w_s1 = (const float*)d_in[1];
    const float* g_s1 = (const float*)d_in[2];
    const float* b_s1 = (const float*)d_in[3];
    const float* w11  = (const float*)d_in[4];
    const float* g11  = (const float*)d_in[5];
    const float* b11  = (const float*)d_in[6];
    const float* w12  = (const float*)d_in[7];
    const float* g12  = (const float*)d_in[8];
    const float* b12  = (const float*)d_in[9];
    const float* w21  = (const float*)d_in[10];
    const float* g21  = (const float*)d_in[11];
    const float* b21  = (const float*)d_in[12];
    const float* w22  = (const float*)d_in[13];
    const float* g22  = (const float*)d_in[14];
    const float* b22  = (const float*)d_in[15];
    const float* w_s2 = (const float*)d_in[16];
    const float* g_s2 = (const float*)d_in[17];
    const float* b_s2 = (const float*)d_in[18];
    const int* nb1 = (const int*)d_in[19];
    const int* nbs = (const int*)d_in[20];
    const int* nb2 = (const int*)d_in[21];

    const int N0 = in_sizes[0] / 256;   // 9216
    const int M1 = in_sizes[19] / 27;   // 27648
    const int M2 = in_sizes[21] / 27;   // 46080

    char* base = (char*)d_ws;
    size_t off = 0;
    auto alloc = [&](size_t bytes) -> char* {
        off = (off + 255) & ~(size_t)255;
        char* p = base + off;
        off += bytes;
        return p;
    };
    bf16_t* xh   = (bf16_t*)alloc((size_t)N0 * 256 * 2);
    bf16_t* xl   = (bf16_t*)alloc((size_t)N0 * 256 * 2);
    bf16_t* w1h  = (bf16_t*)alloc(27UL * 128 * 256 * 2);
    bf16_t* w1l  = (bf16_t*)alloc(27UL * 128 * 256 * 2);
    bf16_t* w11h = (bf16_t*)alloc(27UL * 128 * 128 * 2);
    bf16_t* w11l = (bf16_t*)alloc(27UL * 128 * 128 * 2);
    bf16_t* w12h = (bf16_t*)alloc(27UL * 128 * 128 * 2);
    bf16_t* w12l = (bf16_t*)alloc(27UL * 128 * 128 * 2);
    bf16_t* w21h = (bf16_t*)alloc(27UL * 128 * 128 * 2);
    bf16_t* w21l = (bf16_t*)alloc(27UL * 128 * 128 * 2);
    bf16_t* w22h = (bf16_t*)alloc(27UL * 128 * 128 * 2);
    bf16_t* w22l = (bf16_t*)alloc(27UL * 128 * 128 * 2);
    bf16_t* w2h  = (bf16_t*)alloc(27UL * 32 * 128 * 2);
    bf16_t* w2l  = (bf16_t*)alloc(27UL * 32 * 128 * 2);
    bf16_t* fAh  = (bf16_t*)alloc((size_t)M1 * 128 * 2);
    bf16_t* fAl  = (bf16_t*)alloc((size_t)M1 * 128 * 2);
    bf16_t* fBh  = (bf16_t*)alloc((size_t)M1 * 128 * 2);
    bf16_t* fBl  = (bf16_t*)alloc((size_t)M1 * 128 * 2);
    float*  cbuf = (float*)alloc((size_t)M1 * 128 * 4);   // also covers M2*32
    float*  stats = (float*)alloc(6UL * 256 * 4);         // 6 layers x 2*C
    bf16_t* zrow  = (bf16_t*)alloc(256 * 2);              // zero row for invalid taps

    // stats (6144 B) + zrow (512 B) are contiguous: zero both (ws is poisoned 0xAA)
    zerof<<<7, 256, 0, stream>>>(stats, 1664);

    long nx = (long)N0 * 256;
    split_k<<<(int)((nx + 255) / 256), 256, 0, stream>>>(x, xh, xl, nx);
    wtrans<<<(27 * 256 * 128 + 255) / 256, 256, 0, stream>>>(w_s1, w1h, w1l, 256, 128);
    wtrans<<<(27 * 128 * 128 + 255) / 256, 256, 0, stream>>>(w11, w11h, w11l, 128, 128);
    wtrans<<<(27 * 128 * 128 + 255) / 256, 256, 0, stream>>>(w12, w12h, w12l, 128, 128);
    wtrans<<<(27 * 128 * 128 + 255) / 256, 256, 0, stream>>>(w21, w21h, w21l, 128, 128);
    wtrans<<<(27 * 128 * 128 + 255) / 256, 256, 0, stream>>>(w22, w22h, w22l, 128, 128);
    wtrans<<<(27 * 128 * 32 + 255) / 256, 256, 0, stream>>>(w_s2, w2h, w2l, 128, 32);

    const float inv1 = 1.f / (float)M1, inv2 = 1.f / (float)M2;
    const int gconv = M1 / 32;                   // 864 blocks (32 rows/block, col-split)
    const long e1 = (long)M1 * 128;
    const int gapp1 = (int)((e1 + 255) / 256);

    // L1: spconv1 (256 -> 128)
    conv_mfma<256, 128, 2, 4><<<gconv, 256, 0, stream>>>(xh, xl, nb1, w1h, w1l, zrow, cbuf, stats, M1);
    bn_apply<<<gapp1, 256, 0, stream>>>(cbuf, stats, g_s1, b_s1, nullptr, nullptr,
                                        fAh, fAl, nullptr, e1, 128, inv1);
    // Block 1
    conv_mfma<128, 128, 2, 4><<<gconv, 256, 0, stream>>>(fAh, fAl, nbs, w11h, w11l, zrow, cbuf, stats + 256, M1);
    bn_apply<<<gapp1, 256, 0, stream>>>(cbuf, stats + 256, g11, b11, nullptr, nullptr,
                                        fBh, fBl, nullptr, e1, 128, inv1);
    conv_mfma<128, 128, 2, 4><<<gconv, 256, 0, stream>>>(fBh, fBl, nbs, w12h, w12l, zrow, cbuf, stats + 512, M1);
    bn_apply<<<gapp1, 256, 0, stream>>>(cbuf, stats + 512, g12, b12, fAh, fAl,
                                        fAh, fAl, nullptr, e1, 128, inv1);
    // Block 2
    conv_mfma<128, 128, 2, 4><<<gconv, 256, 0, stream>>>(fAh, fAl, nbs, w21h, w21l, zrow, cbuf, stats + 768, M1);
    bn_apply<<<gapp1, 256, 0, stream>>>(cbuf, stats + 768, g21, b21, nullptr, nullptr,
                                        fBh, fBl, nullptr, e1, 128, inv1);
    conv_mfma<128, 128, 2, 4><<<gconv, 256, 0, stream>>>(fBh, fBl, nbs, w22h, w22l, zrow, cbuf, stats + 1024, M1);
    bn_apply<<<gapp1, 256, 0, stream>>>(cbuf, stats + 1024, g22, b22, fAh, fAl,
                                        fAh, fAl, nullptr, e1, 128, inv1);
    // L6: spconv2 (128 -> 32), final output fp32. Row-split waves (COUT=32: 2 tiles).
    conv_mfma<128, 32, 1, 1><<<M2 / 64, 256, 0, stream>>>(fAh, fAl, nb2, w2h, w2l, zrow, cbuf, stats + 1280, M2);
    const long e2 = (long)M2 * 32;
    bn_apply<<<(int)((e2 + 255) / 256), 256, 0, stream>>>(cbuf, stats + 1280, g_s2, b_s2,
                                                          nullptr, nullptr, nullptr, nullptr,
                                                          (float*)d_out, e2, 32, inv2);
}

// Round 3
// 912.384 us; speedup vs baseline: 2.0638x; 2.0638x over previous
//
#include <hip/hip_runtime.h>
#include <stdint.h>

typedef _Float16 f16;
typedef _Float16 f16x8 __attribute__((ext_vector_type(8)));
typedef _Float16 f16x4 __attribute__((ext_vector_type(4)));
typedef float f32x4 __attribute__((ext_vector_type(4)));

#define GAS __attribute__((address_space(1)))
#define LAS __attribute__((address_space(3)))

// async global->LDS, 16 B per lane; LDS dest = base + lane*16 (wave-uniform base)
__device__ __forceinline__ void gl_lds16(const void* g, void* l) {
    __builtin_amdgcn_global_load_lds((const GAS uint32_t*)g, (LAS uint32_t*)l, 16, 0, 0);
}

__global__ __launch_bounds__(256) void zerof(float* __restrict__ p, int n) {
    int i = blockIdx.x * 256 + threadIdx.x;
    if (i < n) p[i] = 0.f;
}

__global__ __launch_bounds__(256) void cvt16(const float* __restrict__ in,
                                             f16* __restrict__ o, long n) {
    long i = (long)blockIdx.x * 256 + threadIdx.x;
    if (i < n) o[i] = (f16)in[i];
}

// w [27][Cin][Cout] fp32 -> wt [27][Cout][Cin] fp16 (B-fragment: 16B contiguous Cin)
__global__ __launch_bounds__(256) void wtrans16(const float* __restrict__ w,
                                                f16* __restrict__ wt,
                                                int Cin, int Cout) {
    long i = (long)blockIdx.x * 256 + threadIdx.x;
    long total = 27L * Cin * Cout;
    if (i >= total) return;
    int ci = (int)(i % Cin);
    long t = i / Cin;
    int co = (int)(t % Cout);
    int k  = (int)(t / Cout);
    wt[i] = (f16)w[((long)k * Cin + ci) * Cout + co];
}

// Gather-GEMM, m97-style: per tap, stage gathered A rows (128 x 128ch fp16 = 32 KB)
// + B panel (COUT x 128ch = COUT*256 B) into LDS via global_load_lds, then MFMA from
// ds_read_b128. XOR swizzle (chunk ^ (row&7)) applied on the SOURCE address keeps the
// lane-contiguous LDS dest constraint and makes fragment reads 2-way bank-aliased (free).
// KSPL: K-tiles of 128 channels per tap (CIN = KSPL*128).
template <int KSPL, int COUT>
__global__ __launch_bounds__(256) void conv_mfma(
    const f16* __restrict__ fin, const int* __restrict__ nb,
    const f16* __restrict__ wt, const f16* __restrict__ zrow,
    float* __restrict__ out, float* __restrict__ stats, int M) {
    constexpr int CINB = KSPL * 256;             // bytes per full input row
    constexpr int NCHB = COUT / 4;               // B chunks (1 KB = 4 cols)
    constexpr int RT = (COUT == 128) ? 4 : 2;    // 16-row tiles per wave
    constexpr int CT = (COUT == 128) ? 4 : 2;    // 16-col tiles per wave
    extern __shared__ char smem[];
    char* ldsA = smem;                           // 32 KB
    char* ldsB = smem + 32 * 1024;               // COUT*256 B
    __shared__ int tapmask;

    const int tid = threadIdx.x;
    const int lane = tid & 63;
    const int wave = tid >> 6;
    const int q = lane >> 4;
    const int r16 = lane & 15;
    const int rowbase = blockIdx.x * 128;
    const int wr = (COUT == 128) ? (wave >> 1) * 64 : wave * 32;
    const int wc = (COUT == 128) ? (wave & 1) * 64 : 0;

    // per-block tap-valid mask (one pass; 64-lane groups stay within one tap)
    if (tid == 0) tapmask = 0;
    __syncthreads();
    for (int g = tid; g < 27 * 128; g += 256) {
        int k = g >> 7;
        int v = nb[(long)k * M + rowbase + (g & 127)];
        unsigned long long b = __ballot(v >= 0);
        if (b && lane == 0) atomicOr(&tapmask, 1 << k);
    }
    __syncthreads();
    const int mask = tapmask;

    f32x4 acc[RT][CT];
#pragma unroll
    for (int t = 0; t < RT; t++)
#pragma unroll
        for (int c = 0; c < CT; c++) acc[t][c] = f32x4{0.f, 0.f, 0.f, 0.f};

    for (int kt = 0; kt < 27 * KSPL; kt++) {
        const int k = (KSPL == 2) ? (kt >> 1) : kt;
        if (!((mask >> k) & 1)) continue;        // block-uniform skip
        const int half = (KSPL == 2) ? (kt & 1) : 0;
        // stage A: 32 chunks x (4 rows x 256 B); invalid rows read the zero row
        for (int ch = wave; ch < 32; ch += 4) {
            int r = ch * 4 + q;
            int idx = nb[(long)k * M + rowbase + r];
            int cc = r16 ^ (r & 7);
            const char* src = (idx >= 0)
                ? (const char*)fin + (long)idx * CINB + half * 256 + cc * 16
                : (const char*)zrow + cc * 16;
            gl_lds16(src, ldsA + ch * 1024);
        }
        // stage B: contiguous panel [COUT][128ch]
        for (int ch = wave; ch < NCHB; ch += 4) {
            int col = ch * 4 + q;
            int cc = r16 ^ (col & 7);
            const char* src = (const char*)wt + ((long)k * COUT + col) * CINB +
                              half * 256 + cc * 16;
            gl_lds16(src, ldsB + ch * 1024);
        }
        __syncthreads();   // drains vmcnt (global_load_lds) + orders LDS
#pragma unroll
        for (int kk = 0; kk < 4; kk++) {
            const int c16 = kk * 4 + q;
            f16x8 A[RT], B[CT];
#pragma unroll
            for (int t = 0; t < RT; t++) {
                int r = wr + t * 16 + r16;
                A[t] = *(const f16x8*)(ldsA + r * 256 + ((c16 ^ (r & 7)) << 4));
            }
#pragma unroll
            for (int c = 0; c < CT; c++) {
                int col = wc + c * 16 + r16;
                B[c] = *(const f16x8*)(ldsB + col * 256 + ((c16 ^ (col & 7)) << 4));
            }
#pragma unroll
            for (int t = 0; t < RT; t++)
#pragma unroll
                for (int c = 0; c < CT; c++)
                    acc[t][c] = __builtin_amdgcn_mfma_f32_16x16x32_f16(A[t], B[c], acc[t][c], 0, 0, 0);
        }
        __syncthreads();   // protect LDS from next tap's staging
    }
    // D layout: row = quad*4 + reg, col = lane&15. Write + fused BN stats.
#pragma unroll
    for (int c = 0; c < CT; c++) {
        float s = 0.f, ss = 0.f;
#pragma unroll
        for (int t = 0; t < RT; t++)
#pragma unroll
            for (int r = 0; r < 4; r++) {
                float v = acc[t][c][r];
                out[(long)(rowbase + wr + t * 16 + q * 4 + r) * COUT + wc + c * 16 + r16] = v;
                s += v;
                ss = fmaf(v, v, ss);
            }
        s += __shfl_xor(s, 16);
        s += __shfl_xor(s, 32);
        ss += __shfl_xor(ss, 16);
        ss += __shfl_xor(ss, 32);
        if (q == 0) {
            atomicAdd(&stats[wc + c * 16 + r16], s);
            atomicAdd(&stats[COUT + wc + c * 16 + r16], ss);
        }
    }
}

// BN(train) + optional residual + ReLU, 4 elems/thread.
__global__ __launch_bounds__(256) void bn_apply4(
    const float4* __restrict__ f, const float* __restrict__ sums,
    const float* __restrict__ g, const float* __restrict__ bta,
    const f16x4* __restrict__ idn, f16* __restrict__ outh,
    float4* __restrict__ outf, long n4, int C, float invM) {
    long i = (long)blockIdx.x * 256 + threadIdx.x;
    if (i >= n4) return;
    int col0 = (int)((i * 4) & (C - 1));
    float4 v = f[i];
    float r[4] = {v.x, v.y, v.z, v.w};
    f16x4 id = {};
    if (idn) id = idn[i];
    f16x4 ho;
#pragma unroll
    for (int j = 0; j < 4; j++) {
        int c = col0 + j;
        float mu = sums[c] * invM;
        float var = sums[C + c] * invM - mu * mu;
        var = fmaxf(var, 0.f);
        float sc = g[c] * rsqrtf(var + 1e-5f);
        float x = (r[j] - mu) * sc + bta[c];
        if (idn) x += (float)id[j];
        x = fmaxf(x, 0.f);
        r[j] = x;
        ho[j] = (f16)x;
    }
    if (outf) outf[i] = make_float4(r[0], r[1], r[2], r[3]);
    else *(f16x4*)(outh + i * 4) = ho;
}

extern "C" void kernel_launch(void* const* d_in, const int* in_sizes, int n_in,
                              void* d_out, int out_size, void* d_ws, size_t ws_size,
                              hipStream_t stream) {
    (void)n_in; (void)out_size; (void)ws_size;
    const float* x    = (const float*)d_in[0];
    const float* w_s1 = (const float*)d_in[1];
    const float* g_s1 = (const float*)d_in[2];
    const float* b_s1 = (const float*)d_in[3];
    const float* w11  = (const float*)d_in[4];
    const float* g11  = (const float*)d_in[5];
    const float* b11  = (const float*)d_in[6];
    const float* w12  = (const float*)d_in[7];
    const float* g12  = (const float*)d_in[8];
    const float* b12  = (const float*)d_in[9];
    const float* w21  = (const float*)d_in[10];
    const float* g21  = (const float*)d_in[11];
    const float* b21  = (const float*)d_in[12];
    const float* w22  = (const float*)d_in[13];
    const float* g22  = (const float*)d_in[14];
    const float* b22  = (const float*)d_in[15];
    const float* w_s2 = (const float*)d_in[16];
    const float* g_s2 = (const float*)d_in[17];
    const float* b_s2 = (const float*)d_in[18];
    const int* nb1 = (const int*)d_in[19];
    const int* nbs = (const int*)d_in[20];
    const int* nb2 = (const int*)d_in[21];

    const int N0 = in_sizes[0] / 256;   // 9216
    const int M1 = in_sizes[19] / 27;   // 27648
    const int M2 = in_sizes[21] / 27;   // 46080

    char* base = (char*)d_ws;
    size_t off = 0;
    auto alloc = [&](size_t bytes) -> char* {
        off = (off + 255) & ~(size_t)255;
        char* p = base + off;
        off += bytes;
        return p;
    };
    f16* xh  = (f16*)alloc((size_t)N0 * 256 * 2);
    f16* w1  = (f16*)alloc(27UL * 128 * 256 * 2);
    f16* wa1 = (f16*)alloc(27UL * 128 * 128 * 2);
    f16* wa2 = (f16*)alloc(27UL * 128 * 128 * 2);
    f16* wb1 = (f16*)alloc(27UL * 128 * 128 * 2);
    f16* wb2 = (f16*)alloc(27UL * 128 * 128 * 2);
    f16* w2  = (f16*)alloc(27UL * 32 * 128 * 2);
    f16* fA  = (f16*)alloc((size_t)M1 * 128 * 2);
    f16* fB  = (f16*)alloc((size_t)M1 * 128 * 2);
    float* cbuf  = (float*)alloc((size_t)M1 * 128 * 4);  // covers M2*32 too
    float* stats = (float*)alloc(1344UL * 4);            // 5x256 + 64
    f16*   zrow  = (f16*)alloc(512);                     // zero row (256ch max... 512B)

    // stats (5376 B) + zrow (512 B) contiguous -> zero 1472 floats
    zerof<<<6, 256, 0, stream>>>(stats, 1472);

    long nx = (long)N0 * 256;
    cvt16<<<(int)((nx + 255) / 256), 256, 0, stream>>>(x, xh, nx);
    wtrans16<<<(27 * 256 * 128 + 255) / 256, 256, 0, stream>>>(w_s1, w1, 256, 128);
    wtrans16<<<(27 * 128 * 128 + 255) / 256, 256, 0, stream>>>(w11, wa1, 128, 128);
    wtrans16<<<(27 * 128 * 128 + 255) / 256, 256, 0, stream>>>(w12, wa2, 128, 128);
    wtrans16<<<(27 * 128 * 128 + 255) / 256, 256, 0, stream>>>(w21, wb1, 128, 128);
    wtrans16<<<(27 * 128 * 128 + 255) / 256, 256, 0, stream>>>(w22, wb2, 128, 128);
    wtrans16<<<(27 * 128 * 32 + 255) / 256, 256, 0, stream>>>(w_s2, w2, 128, 32);

    const float inv1 = 1.f / (float)M1, inv2 = 1.f / (float)M2;
    const int g1 = M1 / 128;            // 216
    const int g2 = M2 / 128;            // 360
    const int lds128 = 32 * 1024 + 128 * 256;   // 64 KB
    const int lds32  = 32 * 1024 + 32 * 256;    // 40 KB
    const long n4a = (long)M1 * 128 / 4;
    const long n4b = (long)M2 * 32 / 4;
    const int ga = (int)((n4a + 255) / 256);
    const int gb = (int)((n4b + 255) / 256);

    // L1: spconv1 (256 -> 128)
    conv_mfma<2, 128><<<g1, 256, lds128, stream>>>(xh, nb1, w1, zrow, cbuf, stats, M1);
    bn_apply4<<<ga, 256, 0, stream>>>((float4*)cbuf, stats, g_s1, b_s1,
                                      nullptr, fA, nullptr, n4a, 128, inv1);
    // Block 1
    conv_mfma<1, 128><<<g1, 256, lds128, stream>>>(fA, nbs, wa1, zrow, cbuf, stats + 256, M1);
    bn_apply4<<<ga, 256, 0, stream>>>((float4*)cbuf, stats + 256, g11, b11,
                                      nullptr, fB, nullptr, n4a, 128, inv1);
    conv_mfma<1, 128><<<g1, 256, lds128, stream>>>(fB, nbs, wa2, zrow, cbuf, stats + 512, M1);
    bn_apply4<<<ga, 256, 0, stream>>>((float4*)cbuf, stats + 512, g12, b12,
                                      (const f16x4*)fA, fA, nullptr, n4a, 128, inv1);
    // Block 2
    conv_mfma<1, 128><<<g1, 256, lds128, stream>>>(fA, nbs, wb1, zrow, cbuf, stats + 768, M1);
    bn_apply4<<<ga, 256, 0, stream>>>((float4*)cbuf, stats + 768, g21, b21,
                                      nullptr, fB, nullptr, n4a, 128, inv1);
    conv_mfma<1, 128><<<g1, 256, lds128, stream>>>(fB, nbs, wb2, zrow, cbuf, stats + 1024, M1);
    bn_apply4<<<ga, 256, 0, stream>>>((float4*)cbuf, stats + 1024, g22, b22,
                                      (const f16x4*)fA, fA, nullptr, n4a, 128, inv1);
    // L6: spconv2 (128 -> 32), final fp32 output
    conv_mfma<1, 32><<<g2, 256, lds32, stream>>>(fA, nb2, w2, zrow, cbuf, stats + 1280, M2);
    bn_apply4<<<gb, 256, 0, stream>>>((float4*)cbuf, stats + 1280, g_s2, b_s2,
                                      nullptr, nullptr, (float4*)d_out, n4b, 32, inv2);
}

// Round 4
// 699.249 us; speedup vs baseline: 2.6928x; 1.3048x over previous
//
#include <hip/hip_runtime.h>
#include <stdint.h>

typedef _Float16 f16;
typedef _Float16 f16x8 __attribute__((ext_vector_type(8)));
typedef _Float16 f16x4 __attribute__((ext_vector_type(4)));
typedef float f32x4 __attribute__((ext_vector_type(4)));

#define GAS __attribute__((address_space(1)))
#define LAS __attribute__((address_space(3)))

// async global->LDS, 16 B per lane; LDS dest = wave-uniform base + lane*16
__device__ __forceinline__ void gl_lds16(const void* g, void* l) {
    __builtin_amdgcn_global_load_lds((const GAS uint32_t*)g, (LAS uint32_t*)l, 16, 0, 0);
}

__global__ __launch_bounds__(256) void zerof(float* __restrict__ p, int n) {
    int i = blockIdx.x * 256 + threadIdx.x;
    if (i < n) p[i] = 0.f;
}

__global__ __launch_bounds__(256) void cvt16(const float* __restrict__ in,
                                             f16* __restrict__ o, long n) {
    long i = (long)blockIdx.x * 256 + threadIdx.x;
    if (i < n) o[i] = (f16)in[i];
}

// w [27][Cin][Cout] fp32 -> wt [27][Cout][Cin] fp16 (B-fragment: 16B contiguous Cin)
__global__ __launch_bounds__(256) void wtrans16(const float* __restrict__ w,
                                                f16* __restrict__ wt,
                                                int Cin, int Cout) {
    long i = (long)blockIdx.x * 256 + threadIdx.x;
    long total = 27L * Cin * Cout;
    if (i >= total) return;
    int ci = (int)(i % Cin);
    long t = i / Cin;
    int co = (int)(t % Cout);
    int k  = (int)(t / Cout);
    wt[i] = (f16)w[((long)k * Cin + ci) * Cout + co];
}

// Dense implicit 3x3x3 conv over z-plane-stacked 96x96 feature planes.
// The "sparse" coords are dense z-slabs in z-major/y/x row-major order, so the
// rulebook == zero-padded stencil in (y,x) + a plane mapping in z. No nb reads.
// Block tile: 64 out rows = 4y x 16x of ONE out plane. Per z-stage: stage a
// 6y x 18x halo slab (128ch fp16 = 27648 B) into LDS via global_load_lds
// (addresses pure arithmetic; OOB sites read zrow), double-buffered across
// stages; all 9 (dy,dx) taps then read the slab at constant offsets.
// XOR swizzle cc = r16 ^ (site&7) on source -> frag ds_reads are 2-way (free).
// Waves 2x2: wr=(wave>>1)*32 rows, wc=(wave&1)*(COUT/2) cols. B-frags from
// global (weights L2-resident). Epilogue: fused BN sum/sumsq atomics.
// LAYER 0: CIN=256 (2 halves, 1 in-plane, dz=1-p), COUT=128, grid 3*144
// LAYER 1: CIN=128, 3 in-planes, j=p+dz,      COUT=128, grid 3*144
// LAYER 2: CIN=128, 3 in-planes, j=p+dz-1,    COUT=32,  grid 5*144
template <int LAYER>
__global__ __launch_bounds__(256, 2) void conv_dense(
    const f16* __restrict__ fin, const f16* __restrict__ wt,
    const f16* __restrict__ zrow, float* __restrict__ out,
    float* __restrict__ stats) {
    constexpr int COUT = (LAYER == 2) ? 32 : 128;
    constexpr int INRB = (LAYER == 0) ? 512 : 256;   // input row bytes
    constexpr int WRB  = (LAYER == 0) ? 512 : 256;   // weight row bytes per col
    constexpr int RT = 2;
    constexpr int CT = (LAYER == 2) ? 1 : 4;
    __shared__ char lds[2][6 * 18 * 256];            // 2 x 27648 B

    const int b = blockIdx.x;
    const int p = b / 144;                // out plane
    const int t = b % 144;
    const int y0 = (t / 6) * 4;
    const int x0 = (t % 6) * 16;
    const int tid = threadIdx.x;
    const int lane = tid & 63;
    const int wave = tid >> 6;
    const int q = lane >> 4;
    const int r16 = lane & 15;
    const int wr = (wave >> 1) * 32;
    const int wc = (wave & 1) * (CT * 16);

    // stage list (block-uniform)
    int S = 0;
    int js[3], dzs[3], hs[3];
    if (LAYER == 0) {
        js[0] = 0; dzs[0] = 1 - p; hs[0] = 0;
        js[1] = 0; dzs[1] = 1 - p; hs[1] = 1;
        S = 2;
    } else if (LAYER == 1) {
        for (int dz = -1; dz <= 1; dz++) {
            int j = p + dz;
            if (0 <= j && j < 3) { js[S] = j; dzs[S] = dz; hs[S] = 0; S++; }
        }
    } else {
        for (int dz = -1; dz <= 1; dz++) {
            int j = p + dz - 1;
            if (0 <= j && j < 3) { js[S] = j; dzs[S] = dz; hs[S] = 0; S++; }
        }
    }

    auto stage = [&](int s, char* buf) {
        const int j = js[s], h = hs[s];
        const long pbase = (long)j * 9216;
        for (int ch = wave; ch < 27; ch += 4) {
            int site = ch * 4 + q;
            int sy = site / 18;
            int sx = site - sy * 18;
            int y = y0 - 1 + sy;
            int x = x0 - 1 + sx;
            int cc = r16 ^ (site & 7);
            bool ok = ((unsigned)y < 96u) & ((unsigned)x < 96u);
            const char* src = ok
                ? (const char*)fin + (pbase + y * 96 + x) * INRB + h * 256 + cc * 16
                : (const char*)zrow + cc * 16;
            gl_lds16(src, buf + ch * 1024);
        }
    };

    f32x4 acc[RT][CT];
#pragma unroll
    for (int tr = 0; tr < RT; tr++)
#pragma unroll
        for (int c = 0; c < CT; c++) acc[tr][c] = f32x4{0.f, 0.f, 0.f, 0.f};

    stage(0, lds[0]);
    const int sbase = (wr / 16 + 1) * 18 + 1 + r16;   // slab site at (dy,dx)=(0,0), tr=0
    for (int s = 0; s < S; s++) {
        __syncthreads();    // stage(s) DMA drained; buf[(s+1)&1] free
        if (s + 1 < S) stage(s + 1, lds[(s + 1) & 1]);
        const char* buf = lds[s & 1];
        const int dz = dzs[s], h = hs[s];
#pragma unroll
        for (int dy = -1; dy <= 1; dy++) {
#pragma unroll
            for (int dx = -1; dx <= 1; dx++) {
                const int k = (dz + 1) * 9 + (dy + 1) * 3 + (dx + 1);
                const char* wb = (const char*)wt + (long)(k * COUT + wc + r16) * WRB +
                                 h * 256 + q * 16;
#pragma unroll
                for (int kk = 0; kk < 4; kk++) {
                    f16x8 Af[RT], Bf[CT];
#pragma unroll
                    for (int tr = 0; tr < RT; tr++) {
                        int site = sbase + (tr + dy) * 18 + dx;
                        Af[tr] = *(const f16x8*)(buf + site * 256 +
                                                 (((kk * 4 + q) ^ (site & 7)) << 4));
                    }
#pragma unroll
                    for (int c = 0; c < CT; c++)
                        Bf[c] = *(const f16x8*)(wb + (long)c * 16 * WRB + kk * 64);
#pragma unroll
                    for (int tr = 0; tr < RT; tr++)
#pragma unroll
                        for (int c = 0; c < CT; c++)
                            acc[tr][c] = __builtin_amdgcn_mfma_f32_16x16x32_f16(
                                Af[tr], Bf[c], acc[tr][c], 0, 0, 0);
                }
            }
        }
    }
    // Epilogue: D row = q*4+reg within 16-row (x) tile; write + fused BN stats.
    const long mbase = (long)p * 9216 + (long)y0 * 96 + x0;
#pragma unroll
    for (int c = 0; c < CT; c++) {
        const int col = wc + c * 16 + r16;
        float sum = 0.f, ssq = 0.f;
#pragma unroll
        for (int tr = 0; tr < RT; tr++) {
            const int ly = wr / 16 + tr;
#pragma unroll
            for (int r = 0; r < 4; r++) {
                const int lx = q * 4 + r;
                float v = acc[tr][c][r];
                out[(mbase + ly * 96 + lx) * COUT + col] = v;
                sum += v;
                ssq = fmaf(v, v, ssq);
            }
        }
        sum += __shfl_xor(sum, 16);
        sum += __shfl_xor(sum, 32);
        ssq += __shfl_xor(ssq, 16);
        ssq += __shfl_xor(ssq, 32);
        if (q == 0) {
            atomicAdd(&stats[col], sum);
            atomicAdd(&stats[COUT + col], ssq);
        }
    }
}

// BN(train) + optional residual + ReLU, 4 elems/thread.
__global__ __launch_bounds__(256) void bn_apply4(
    const float4* __restrict__ f, const float* __restrict__ sums,
    const float* __restrict__ g, const float* __restrict__ bta,
    const f16x4* __restrict__ idn, f16* __restrict__ outh,
    float4* __restrict__ outf, long n4, int C, float invM) {
    long i = (long)blockIdx.x * 256 + threadIdx.x;
    if (i >= n4) return;
    int col0 = (int)((i * 4) & (C - 1));
    float4 v = f[i];
    float r[4] = {v.x, v.y, v.z, v.w};
    f16x4 id = {};
    if (idn) id = idn[i];
    f16x4 ho;
#pragma unroll
    for (int j = 0; j < 4; j++) {
        int c = col0 + j;
        float mu = sums[c] * invM;
        float var = sums[C + c] * invM - mu * mu;
        var = fmaxf(var, 0.f);
        float sc = g[c] * rsqrtf(var + 1e-5f);
        float x = (r[j] - mu) * sc + bta[c];
        if (idn) x += (float)id[j];
        x = fmaxf(x, 0.f);
        r[j] = x;
        ho[j] = (f16)x;
    }
    if (outf) outf[i] = make_float4(r[0], r[1], r[2], r[3]);
    else *(f16x4*)(outh + i * 4) = ho;
}

extern "C" void kernel_launch(void* const* d_in, const int* in_sizes, int n_in,
                              void* d_out, int out_size, void* d_ws, size_t ws_size,
                              hipStream_t stream) {
    (void)n_in; (void)out_size; (void)ws_size;
    const float* x    = (const float*)d_in[0];
    const float* w_s1 = (const float*)d_in[1];
    const float* g_s1 = (const float*)d_in[2];
    const float* b_s1 = (const float*)d_in[3];
    const float* w11  = (const float*)d_in[4];
    const float* g11  = (const float*)d_in[5];
    const float* b11  = (const float*)d_in[6];
    const float* w12  = (const float*)d_in[7];
    const float* g12  = (const float*)d_in[8];
    const float* b12  = (const float*)d_in[9];
    const float* w21  = (const float*)d_in[10];
    const float* g21  = (const float*)d_in[11];
    const float* b21  = (const float*)d_in[12];
    const float* w22  = (const float*)d_in[13];
    const float* g22  = (const float*)d_in[14];
    const float* b22  = (const float*)d_in[15];
    const float* w_s2 = (const float*)d_in[16];
    const float* g_s2 = (const float*)d_in[17];
    const float* b_s2 = (const float*)d_in[18];

    const int N0 = in_sizes[0] / 256;   // 9216
    const int M1 = in_sizes[19] / 27;   // 27648
    const int M2 = in_sizes[21] / 27;   // 46080

    char* base = (char*)d_ws;
    size_t off = 0;
    auto alloc = [&](size_t bytes) -> char* {
        off = (off + 255) & ~(size_t)255;
        char* p = base + off;
        off += bytes;
        return p;
    };
    f16* xh  = (f16*)alloc((size_t)N0 * 256 * 2);
    f16* w1  = (f16*)alloc(27UL * 128 * 256 * 2);
    f16* wa1 = (f16*)alloc(27UL * 128 * 128 * 2);
    f16* wa2 = (f16*)alloc(27UL * 128 * 128 * 2);
    f16* wb1 = (f16*)alloc(27UL * 128 * 128 * 2);
    f16* wb2 = (f16*)alloc(27UL * 128 * 128 * 2);
    f16* w2  = (f16*)alloc(27UL * 32 * 128 * 2);
    f16* fA  = (f16*)alloc((size_t)M1 * 128 * 2);
    f16* fB  = (f16*)alloc((size_t)M1 * 128 * 2);
    float* cbuf  = (float*)alloc((size_t)M1 * 128 * 4);  // covers M2*32 too
    float* stats = (float*)alloc(1344UL * 4);            // 5x256 + 64
    f16*   zrow  = (f16*)alloc(512);                     // zero site (256B used)

    // stats (5376 B) + zrow (512 B) contiguous -> zero 1472 floats
    zerof<<<6, 256, 0, stream>>>(stats, 1472);

    long nx = (long)N0 * 256;
    cvt16<<<(int)((nx + 255) / 256), 256, 0, stream>>>(x, xh, nx);
    wtrans16<<<(27 * 256 * 128 + 255) / 256, 256, 0, stream>>>(w_s1, w1, 256, 128);
    wtrans16<<<(27 * 128 * 128 + 255) / 256, 256, 0, stream>>>(w11, wa1, 128, 128);
    wtrans16<<<(27 * 128 * 128 + 255) / 256, 256, 0, stream>>>(w12, wa2, 128, 128);
    wtrans16<<<(27 * 128 * 128 + 255) / 256, 256, 0, stream>>>(w21, wb1, 128, 128);
    wtrans16<<<(27 * 128 * 128 + 255) / 256, 256, 0, stream>>>(w22, wb2, 128, 128);
    wtrans16<<<(27 * 128 * 32 + 255) / 256, 256, 0, stream>>>(w_s2, w2, 128, 32);

    const float inv1 = 1.f / (float)M1, inv2 = 1.f / (float)M2;
    const int g1 = 3 * 144;             // 432 blocks (64 rows each)
    const int g2 = 5 * 144;             // 720 blocks
    const long n4a = (long)M1 * 128 / 4;
    const long n4b = (long)M2 * 32 / 4;
    const int ga = (int)((n4a + 255) / 256);
    const int gb = (int)((n4b + 255) / 256);

    // L1: spconv1 (256 -> 128)
    conv_dense<0><<<g1, 256, 0, stream>>>(xh, w1, zrow, cbuf, stats);
    bn_apply4<<<ga, 256, 0, stream>>>((float4*)cbuf, stats, g_s1, b_s1,
                                      nullptr, fA, nullptr, n4a, 128, inv1);
    // Block 1
    conv_dense<1><<<g1, 256, 0, stream>>>(fA, wa1, zrow, cbuf, stats + 256);
    bn_apply4<<<ga, 256, 0, stream>>>((float4*)cbuf, stats + 256, g11, b11,
                                      nullptr, fB, nullptr, n4a, 128, inv1);
    conv_dense<1><<<g1, 256, 0, stream>>>(fB, wa2, zrow, cbuf, stats + 512);
    bn_apply4<<<ga, 256, 0, stream>>>((float4*)cbuf, stats + 512, g12, b12,
                                      (const f16x4*)fA, fA, nullptr, n4a, 128, inv1);
    // Block 2
    conv_dense<1><<<g1, 256, 0, stream>>>(fA, wb1, zrow, cbuf, stats + 768);
    bn_apply4<<<ga, 256, 0, stream>>>((float4*)cbuf, stats + 768, g21, b21,
                                      nullptr, fB, nullptr, n4a, 128, inv1);
    conv_dense<1><<<g1, 256, 0, stream>>>(fB, wb2, zrow, cbuf, stats + 1024);
    bn_apply4<<<ga, 256, 0, stream>>>((float4*)cbuf, stats + 1024, g22, b22,
                                      (const f16x4*)fA, fA, nullptr, n4a, 128, inv1);
    // L6: spconv2 (128 -> 32), final fp32 output
    conv_dense<2><<<g2, 256, 0, stream>>>(fA, w2, zrow, cbuf, stats + 1280);
    bn_apply4<<<gb, 256, 0, stream>>>((float4*)cbuf, stats + 1280, g_s2, b_s2,
                                      nullptr, nullptr, (float4*)d_out, n4b, 32, inv2);
}

// Round 5
// 456.404 us; speedup vs baseline: 4.1256x; 1.5321x over previous
//
#include <hip/hip_runtime.h>
#include <stdint.h>

typedef _Float16 f16;
typedef _Float16 f16x8 __attribute__((ext_vector_type(8)));
typedef _Float16 f16x4 __attribute__((ext_vector_type(4)));
typedef float f32x4 __attribute__((ext_vector_type(4)));

#define GAS __attribute__((address_space(1)))
#define LAS __attribute__((address_space(3)))

// async global->LDS, 16 B per lane; LDS dest = wave-uniform base + lane*16
__device__ __forceinline__ void gl_lds16(const void* g, void* l) {
    __builtin_amdgcn_global_load_lds((const GAS uint32_t*)g, (LAS uint32_t*)l, 16, 0, 0);
}

__global__ __launch_bounds__(256) void zerof(float* __restrict__ p, int n) {
    int i = blockIdx.x * 256 + threadIdx.x;
    if (i < n) p[i] = 0.f;
}

__global__ __launch_bounds__(256) void cvt16(const float* __restrict__ in,
                                             f16* __restrict__ o, long n) {
    long i = (long)blockIdx.x * 256 + threadIdx.x;
    if (i < n) o[i] = (f16)in[i];
}

// w [27][Cin][Cout] fp32 -> wt [27][Cout][Cin] fp16 (B-fragment: 16B contiguous Cin)
__global__ __launch_bounds__(256) void wtrans16(const float* __restrict__ w,
                                                f16* __restrict__ wt,
                                                int Cin, int Cout) {
    long i = (long)blockIdx.x * 256 + threadIdx.x;
    long total = 27L * Cin * Cout;
    if (i >= total) return;
    int ci = (int)(i % Cin);
    long t = i / Cin;
    int co = (int)(t % Cout);
    int k  = (int)(t / Cout);
    wt[i] = (f16)w[((long)k * Cin + ci) * Cout + co];
}

// Dense implicit 3x3x3 conv, fully LDS-fed MFMA:
//  - A: 10y x 18x halo slab (128ch fp16 = 46080 B), double-buffered per z-stage,
//    DMA'd with global_load_lds (OOB sites -> zrow), XOR swizzle on source.
//  - B: per-tap weight panel [COUT][128ch] (32 KB / 8 KB), double-buffered per
//    TAP: iteration t issues DMA for tap t+1, computes tap t from LDS.
//  Block tile: 128 out rows = 8y x 16x of one out plane; 1 block/CU (157 KB LDS).
//  Waves: COUT=128 -> 2x2 (row-half x col-half); COUT=32 -> 4 row-quarters.
// LAYER 0: CIN=256 (2 halves, 1 in-plane, dz=1-p), COUT=128, grid 3*72
// LAYER 1: CIN=128, 3 in-planes, j=p+dz,   COUT=128, grid 3*72
// LAYER 2: CIN=128, 3 in-planes, j=p+dz-1, COUT=32,  grid 5*72
template <int LAYER>
__global__ __launch_bounds__(256, 1) void conv_dense(
    const f16* __restrict__ fin, const f16* __restrict__ wt,
    const f16* __restrict__ zrow, float* __restrict__ out,
    float* __restrict__ stats) {
    constexpr int COUT = (LAYER == 2) ? 32 : 128;
    constexpr int INRB = (LAYER == 0) ? 512 : 256;   // input row bytes
    constexpr int WRB  = (LAYER == 0) ? 512 : 256;   // weight row bytes per col
    constexpr int RT   = (COUT == 128) ? 4 : 2;      // 16-row tiles per wave
    constexpr int CT   = (COUT == 128) ? 4 : 2;      // 16-col tiles per wave
    constexpr int NBCH = COUT / 4;                   // B chunks (1 KB each)
    extern __shared__ char smem[];
    char* ldsA0 = smem;                 // 46080
    char* ldsA1 = smem + 46080;         // 46080
    char* ldsB0 = smem + 92160;         // COUT*256
    char* ldsB1 = smem + 92160 + COUT * 256;

    const int b = blockIdx.x;
    const int p = b / 72;               // out plane
    const int t0 = b % 72;
    const int y0 = (t0 / 6) * 8;
    const int x0 = (t0 % 6) * 16;
    const int tid = threadIdx.x;
    const int lane = tid & 63;
    const int wave = tid >> 6;
    const int q = lane >> 4;
    const int r16 = lane & 15;
    const int wr = ((COUT == 128) ? (wave >> 1) : wave) * (RT * 16);
    const int wc = ((COUT == 128) ? (wave & 1) : 0) * (CT * 16);

    // stage list (block-uniform): z-planes (and channel halves for LAYER 0)
    int S = 0;
    int js[3], dzs[3], hs[3];
    if (LAYER == 0) {
        js[0] = 0; dzs[0] = 1 - p; hs[0] = 0;
        js[1] = 0; dzs[1] = 1 - p; hs[1] = 1;
        S = 2;
    } else if (LAYER == 1) {
        for (int dz = -1; dz <= 1; dz++) {
            int j = p + dz;
            if (0 <= j && j < 3) { js[S] = j; dzs[S] = dz; hs[S] = 0; S++; }
        }
    } else {
        for (int dz = -1; dz <= 1; dz++) {
            int j = p + dz - 1;
            if (0 <= j && j < 3) { js[S] = j; dzs[S] = dz; hs[S] = 0; S++; }
        }
    }

    auto stageA = [&](int s, char* buf) {
        const int j = js[s], h = hs[s];
        const long pbase = (long)j * 9216;
        for (int ch = wave; ch < 45; ch += 4) {
            int site = ch * 4 + q;
            int sy = site / 18;
            int sx = site - sy * 18;
            int y = y0 - 1 + sy;
            int x = x0 - 1 + sx;
            int cc = r16 ^ (site & 7);
            bool ok = ((unsigned)y < 96u) & ((unsigned)x < 96u);
            const char* src = ok
                ? (const char*)fin + (pbase + y * 96 + x) * INRB + h * 256 + cc * 16
                : (const char*)zrow + cc * 16;
            gl_lds16(src, buf + ch * 1024);
        }
    };
    auto stageB = [&](int k, int h, char* buf) {
        for (int ch = wave; ch < NBCH; ch += 4) {
            int col = ch * 4 + q;
            int cc = r16 ^ (col & 7);
            const char* src = (const char*)wt + (long)(k * COUT + col) * WRB +
                              h * 256 + cc * 16;
            gl_lds16(src, buf + ch * 1024);
        }
    };

    f32x4 acc[RT][CT];
#pragma unroll
    for (int tr = 0; tr < RT; tr++)
#pragma unroll
        for (int c = 0; c < CT; c++) acc[tr][c] = f32x4{0.f, 0.f, 0.f, 0.f};

    stageA(0, ldsA0);
    stageB((dzs[0] + 1) * 9, hs[0], ldsB0);

    int tap = 0;
    for (int s = 0; s < S; s++) {
        const char* bufA = (s & 1) ? ldsA1 : ldsA0;
#pragma unroll
        for (int i = 0; i < 9; i++, tap++) {
            __syncthreads();   // drains DMA for tap `tap` (+A stage when due)
            if (i == 0 && s + 1 < S) stageA(s + 1, ((s + 1) & 1) ? ldsA1 : ldsA0);
            if (tap + 1 < S * 9) {
                int sn = (i == 8) ? s + 1 : s;
                int in2 = (i == 8) ? 0 : i + 1;
                stageB((dzs[sn] + 1) * 9 + in2, hs[sn], ((tap + 1) & 1) ? ldsB1 : ldsB0);
            }
            const char* bufB = (tap & 1) ? ldsB1 : ldsB0;
            const int dy = i / 3 - 1, dx = i % 3 - 1;
#pragma unroll
            for (int kk = 0; kk < 4; kk++) {
                f16x8 Af[RT], Bf[CT];
#pragma unroll
                for (int tr = 0; tr < RT; tr++) {
                    int site = (wr / 16 + tr + 1 + dy) * 18 + 1 + dx + r16;
                    Af[tr] = *(const f16x8*)(bufA + site * 256 +
                                             (((kk * 4 + q) ^ (site & 7)) << 4));
                }
#pragma unroll
                for (int c = 0; c < CT; c++) {
                    int col = wc + c * 16 + r16;
                    Bf[c] = *(const f16x8*)(bufB + col * 256 +
                                            (((kk * 4 + q) ^ (col & 7)) << 4));
                }
#pragma unroll
                for (int tr = 0; tr < RT; tr++)
#pragma unroll
                    for (int c = 0; c < CT; c++)
                        acc[tr][c] = __builtin_amdgcn_mfma_f32_16x16x32_f16(
                            Af[tr], Bf[c], acc[tr][c], 0, 0, 0);
            }
        }
    }
    // Epilogue: D row = q*4+reg within 16-row (x) tile; write + fused BN stats.
    const long mbase = (long)p * 9216 + (long)y0 * 96 + x0;
#pragma unroll
    for (int c = 0; c < CT; c++) {
        const int col = wc + c * 16 + r16;
        float sum = 0.f, ssq = 0.f;
#pragma unroll
        for (int tr = 0; tr < RT; tr++) {
            const int ly = wr / 16 + tr;
#pragma unroll
            for (int r = 0; r < 4; r++) {
                const int lx = q * 4 + r;
                float v = acc[tr][c][r];
                out[(mbase + ly * 96 + lx) * COUT + col] = v;
                sum += v;
                ssq = fmaf(v, v, ssq);
            }
        }
        sum += __shfl_xor(sum, 16);
        sum += __shfl_xor(sum, 32);
        ssq += __shfl_xor(ssq, 16);
        ssq += __shfl_xor(ssq, 32);
        if (q == 0) {
            atomicAdd(&stats[col], sum);
            atomicAdd(&stats[COUT + col], ssq);
        }
    }
}

// BN(train) + optional residual + ReLU, 4 elems/thread.
__global__ __launch_bounds__(256) void bn_apply4(
    const float4* __restrict__ f, const float* __restrict__ sums,
    const float* __restrict__ g, const float* __restrict__ bta,
    const f16x4* __restrict__ idn, f16* __restrict__ outh,
    float4* __restrict__ outf, long n4, int C, float invM) {
    long i = (long)blockIdx.x * 256 + threadIdx.x;
    if (i >= n4) return;
    int col0 = (int)((i * 4) & (C - 1));
    float4 v = f[i];
    float r[4] = {v.x, v.y, v.z, v.w};
    f16x4 id = {};
    if (idn) id = idn[i];
    f16x4 ho;
#pragma unroll
    for (int j = 0; j < 4; j++) {
        int c = col0 + j;
        float mu = sums[c] * invM;
        float var = sums[C + c] * invM - mu * mu;
        var = fmaxf(var, 0.f);
        float sc = g[c] * rsqrtf(var + 1e-5f);
        float x = (r[j] - mu) * sc + bta[c];
        if (idn) x += (float)id[j];
        x = fmaxf(x, 0.f);
        r[j] = x;
        ho[j] = (f16)x;
    }
    if (outf) outf[i] = make_float4(r[0], r[1], r[2], r[3]);
    else *(f16x4*)(outh + i * 4) = ho;
}

extern "C" void kernel_launch(void* const* d_in, const int* in_sizes, int n_in,
                              void* d_out, int out_size, void* d_ws, size_t ws_size,
                              hipStream_t stream) {
    (void)n_in; (void)out_size; (void)ws_size;
    const float* x    = (const float*)d_in[0];
    const float* w_s1 = (const float*)d_in[1];
    const float* g_s1 = (const float*)d_in[2];
    const float* b_s1 = (const float*)d_in[3];
    const float* w11  = (const float*)d_in[4];
    const float* g11  = (const float*)d_in[5];
    const float* b11  = (const float*)d_in[6];
    const float* w12  = (const float*)d_in[7];
    const float* g12  = (const float*)d_in[8];
    const float* b12  = (const float*)d_in[9];
    const float* w21  = (const float*)d_in[10];
    const float* g21  = (const float*)d_in[11];
    const float* b21  = (const float*)d_in[12];
    const float* w22  = (const float*)d_in[13];
    const float* g22  = (const float*)d_in[14];
    const float* b22  = (const float*)d_in[15];
    const float* w_s2 = (const float*)d_in[16];
    const float* g_s2 = (const float*)d_in[17];
    const float* b_s2 = (const float*)d_in[18];

    const int N0 = in_sizes[0] / 256;   // 9216
    const int M1 = in_sizes[19] / 27;   // 27648
    const int M2 = in_sizes[21] / 27;   // 46080

    char* base = (char*)d_ws;
    size_t off = 0;
    auto alloc = [&](size_t bytes) -> char* {
        off = (off + 255) & ~(size_t)255;
        char* p = base + off;
        off += bytes;
        return p;
    };
    f16* xh  = (f16*)alloc((size_t)N0 * 256 * 2);
    f16* w1  = (f16*)alloc(27UL * 128 * 256 * 2);
    f16* wa1 = (f16*)alloc(27UL * 128 * 128 * 2);
    f16* wa2 = (f16*)alloc(27UL * 128 * 128 * 2);
    f16* wb1 = (f16*)alloc(27UL * 128 * 128 * 2);
    f16* wb2 = (f16*)alloc(27UL * 128 * 128 * 2);
    f16* w2  = (f16*)alloc(27UL * 32 * 128 * 2);
    f16* fA  = (f16*)alloc((size_t)M1 * 128 * 2);
    f16* fB  = (f16*)alloc((size_t)M1 * 128 * 2);
    float* cbuf  = (float*)alloc((size_t)M1 * 128 * 4);  // covers M2*32 too
    float* stats = (float*)alloc(1344UL * 4);            // 5x256 + 64
    f16*   zrow  = (f16*)alloc(512);                     // zero site (256B used)

    // Enable >64KB dynamic LDS (host-side state; idempotent, capture-safe)
    const int lds01 = 92160 + 2 * 128 * 256;   // 157696
    const int lds2  = 92160 + 2 * 32 * 256;    // 108544
    (void)hipFuncSetAttribute((const void*)conv_dense<0>,
                              hipFuncAttributeMaxDynamicSharedMemorySize, lds01);
    (void)hipFuncSetAttribute((const void*)conv_dense<1>,
                              hipFuncAttributeMaxDynamicSharedMemorySize, lds01);
    (void)hipFuncSetAttribute((const void*)conv_dense<2>,
                              hipFuncAttributeMaxDynamicSharedMemorySize, lds2);

    // stats (5376 B) + zrow (512 B) contiguous -> zero 1472 floats
    zerof<<<6, 256, 0, stream>>>(stats, 1472);

    long nx = (long)N0 * 256;
    cvt16<<<(int)((nx + 255) / 256), 256, 0, stream>>>(x, xh, nx);
    wtrans16<<<(27 * 256 * 128 + 255) / 256, 256, 0, stream>>>(w_s1, w1, 256, 128);
    wtrans16<<<(27 * 128 * 128 + 255) / 256, 256, 0, stream>>>(w11, wa1, 128, 128);
    wtrans16<<<(27 * 128 * 128 + 255) / 256, 256, 0, stream>>>(w12, wa2, 128, 128);
    wtrans16<<<(27 * 128 * 128 + 255) / 256, 256, 0, stream>>>(w21, wb1, 128, 128);
    wtrans16<<<(27 * 128 * 128 + 255) / 256, 256, 0, stream>>>(w22, wb2, 128, 128);
    wtrans16<<<(27 * 128 * 32 + 255) / 256, 256, 0, stream>>>(w_s2, w2, 128, 32);

    const float inv1 = 1.f / (float)M1, inv2 = 1.f / (float)M2;
    const int g1 = 3 * 72;              // 216 blocks (128 rows each)
    const int g2 = 5 * 72;              // 360 blocks
    const long n4a = (long)M1 * 128 / 4;
    const long n4b = (long)M2 * 32 / 4;
    const int ga = (int)((n4a + 255) / 256);
    const int gb = (int)((n4b + 255) / 256);

    // L1: spconv1 (256 -> 128)
    conv_dense<0><<<g1, 256, lds01, stream>>>(xh, w1, zrow, cbuf, stats);
    bn_apply4<<<ga, 256, 0, stream>>>((float4*)cbuf, stats, g_s1, b_s1,
                                      nullptr, fA, nullptr, n4a, 128, inv1);
    // Block 1
    conv_dense<1><<<g1, 256, lds01, stream>>>(fA, wa1, zrow, cbuf, stats + 256);
    bn_apply4<<<ga, 256, 0, stream>>>((float4*)cbuf, stats + 256, g11, b11,
                                      nullptr, fB, nullptr, n4a, 128, inv1);
    conv_dense<1><<<g1, 256, lds01, stream>>>(fB, wa2, zrow, cbuf, stats + 512);
    bn_apply4<<<ga, 256, 0, stream>>>((float4*)cbuf, stats + 512, g12, b12,
                                      (const f16x4*)fA, fA, nullptr, n4a, 128, inv1);
    // Block 2
    conv_dense<1><<<g1, 256, lds01, stream>>>(fA, wb1, zrow, cbuf, stats + 768);
    bn_apply4<<<ga, 256, 0, stream>>>((float4*)cbuf, stats + 768, g21, b21,
                                      nullptr, fB, nullptr, n4a, 128, inv1);
    conv_dense<1><<<g1, 256, lds01, stream>>>(fB, wb2, zrow, cbuf, stats + 1024);
    bn_apply4<<<ga, 256, 0, stream>>>((float4*)cbuf, stats + 1024, g22, b22,
                                      (const f16x4*)fA, fA, nullptr, n4a, 128, inv1);
    // L6: spconv2 (128 -> 32), final fp32 output
    conv_dense<2><<<g2, 256, lds2, stream>>>(fA, w2, zrow, cbuf, stats + 1280);
    bn_apply4<<<gb, 256, 0, stream>>>((float4*)cbuf, stats + 1280, g_s2, b_s2,
                                      nullptr, nullptr, (float4*)d_out, n4b, 32, inv2);
}